// Round 6
// baseline (466.989 us; speedup 1.0000x reference)
//
#include <hip/hip_runtime.h>

#define NSTEPS 20
#define ALPHA  0.9f
#define VTH    1.0f
#define GSOMA  0.3f
#define ISCALE 0.5f

#define NOR  21
#define NORN 42
#define NLN  56
#define NPN  42
#define NKC  2000
#define NOD  34

#define TPB  320   // waves 0-3: KC consumers (256 thr); wave 4: small-net producer
#define KPER 8     // KCs per consumer thread: 250 * 8 = 2000

// One block per batch row. Producer wave simulates ORN->LN->PN one step ahead,
// publishing the PN spike mask to LDS; consumer waves run the KC two-compartment
// + APL dynamics (identical numerics to the verified phase2 kernel).
__global__ __launch_bounds__(TPB)
void snn_fused1(const float* __restrict__ or_input,   // [B,21]
                const float* __restrict__ or_gains,   // [21]
                const float* __restrict__ mapping,    // [21,42]
                const float* __restrict__ orn_to_pn,  // [42,42]
                const float* __restrict__ orn_to_ln,  // [42,56]
                const float* __restrict__ ln_to_pn,   // [56,42]
                const float* __restrict__ pn_to_kc,   // [42,2000]
                const float* __restrict__ kc_to_apl,  // [2000,1]
                const float* __restrict__ apl_to_kc,  // [1,2000]
                const float* __restrict__ dec_w,      // [2000,34]
                const float* __restrict__ dec_b,      // [34]
                float* __restrict__ out)              // [B,34]
{
    __shared__ float sSpg[NOR];
    __shared__ float sRed[2][4];            // APL partials, double-buffered
    __shared__ float sRed2[4 * NOD];        // epilogue reduction
    __shared__ unsigned long long sM[2];    // PN masks, double-buffered

    const int  tid      = threadIdx.x;
    const int  lane     = tid & 63;
    const int  wid      = tid >> 6;         // 0..4
    const bool producer = (tid >= 256);
    const int  b        = blockIdx.x;

    // ---------------- consumer state ----------------
    const int  kbase = producer ? 0 : tid * KPER;
    const bool act   = (!producer) && (tid < 250);
    float vd[KPER], va[KPER], cnt[KPER], wa2k[KPER], wk2a[KPER];
#pragma unroll
    for (int j = 0; j < KPER; ++j) { vd[j] = 0.f; va[j] = 0.f; cnt[j] = 0.f; }

    // ---------------- producer state ----------------
    float v_orn = 0.f, v_ln = 0.f, v_pn = 0.f, drive = 0.f;

    // ---------------- prologue ----------------
    if (producer) {
        if (lane < NOR) sSpg[lane] = log1pf(expf(or_gains[lane]));  // softplus
    } else {
        // vectorized weight staging (kbase is 32B-aligned)
        const float4* a4 = (const float4*)(apl_to_kc + (act ? kbase : 0));
        const float4* k4 = (const float4*)(kc_to_apl + (act ? kbase : 0));
        float4 a0 = a4[0], a1 = a4[1], k0 = k4[0], k1 = k4[1];
        const float g = act ? 1.f : 0.f;
        wa2k[0] = g * a0.x; wa2k[1] = g * a0.y; wa2k[2] = g * a0.z; wa2k[3] = g * a0.w;
        wa2k[4] = g * a1.x; wa2k[5] = g * a1.y; wa2k[6] = g * a1.z; wa2k[7] = g * a1.w;
        wk2a[0] = g * k0.x; wk2a[1] = g * k0.y; wk2a[2] = g * k0.z; wk2a[3] = g * k0.w;
        wk2a[4] = g * k1.x; wk2a[5] = g * k1.y; wk2a[6] = g * k1.z; wk2a[7] = g * k1.w;
        if (tid < 8) sRed[tid >> 2][tid & 3] = 0.f;
    }
    __syncthreads();   // sSpg + sRed zeros visible

    // producer: per-lane ORN drive, then step-0 mask
    if (producer) {
        if (lane < NORN) {
            const float* x = or_input + (long)b * NOR;
            for (int i = 0; i < NOR; ++i)
                drive += x[i] * sSpg[i] * mapping[i * NORN + lane];
            drive *= ISCALE;
        }
    }

    // small-net single step: updates v_orn/v_ln/v_pn, writes mask to sM[slot].
    // Gathers batched 4 bits wide (loads pipelined), accumulation strictly
    // sequential in ascending bit order -> bit-identical to dense sum.
#define SMALLNET_STEP(slot)                                                     \
    do {                                                                        \
        bool so = false;                                                        \
        if (lane < NORN) {                                                      \
            v_orn = ALPHA * v_orn + drive;                                      \
            so = (v_orn - VTH) > 0.f;                                           \
            if (so) v_orn = 0.f;                                                \
        }                                                                       \
        const unsigned long long mOrn = __ballot(so);                           \
        float aln = 0.f, apn = 0.f;                                             \
        {                                                                       \
            unsigned long long m = mOrn;                                        \
            while (m) {                                                         \
                int o0 = __builtin_ctzll(m); m &= m - 1;                        \
                int o1 = o0, o2 = o0, o3 = o0;                                  \
                float f1 = 0.f, f2 = 0.f, f3 = 0.f;                             \
                if (m) { o1 = __builtin_ctzll(m); m &= m - 1; f1 = 1.f; }       \
                if (m) { o2 = __builtin_ctzll(m); m &= m - 1; f2 = 1.f; }       \
                if (m) { o3 = __builtin_ctzll(m); m &= m - 1; f3 = 1.f; }       \
                float l0 = 0.f, l1 = 0.f, l2 = 0.f, l3 = 0.f;                   \
                float p0 = 0.f, p1 = 0.f, p2 = 0.f, p3 = 0.f;                   \
                if (lane < NLN) {                                               \
                    l0 = orn_to_ln[o0 * NLN + lane];                            \
                    l1 = orn_to_ln[o1 * NLN + lane];                            \
                    l2 = orn_to_ln[o2 * NLN + lane];                            \
                    l3 = orn_to_ln[o3 * NLN + lane];                            \
                }                                                               \
                if (lane < NPN) {                                               \
                    p0 = orn_to_pn[o0 * NPN + lane];                            \
                    p1 = orn_to_pn[o1 * NPN + lane];                            \
                    p2 = orn_to_pn[o2 * NPN + lane];                            \
                    p3 = orn_to_pn[o3 * NPN + lane];                            \
                }                                                               \
                aln += l0; aln += f1 * l1; aln += f2 * l2; aln += f3 * l3;      \
                apn += p0; apn += f1 * p1; apn += f2 * p2; apn += f3 * p3;      \
            }                                                                   \
        }                                                                       \
        bool sl = false;                                                        \
        if (lane < NLN) {                                                       \
            v_ln = ALPHA * v_ln + aln;                                          \
            sl = (v_ln - VTH) > 0.f;                                            \
            if (sl) v_ln = 0.f;                                                 \
        }                                                                       \
        const unsigned long long mLn = __ballot(sl);                            \
        float h = 0.f;                                                          \
        {                                                                       \
            unsigned long long m = mLn;                                         \
            while (m) {                                                         \
                int q0 = __builtin_ctzll(m); m &= m - 1;                        \
                int q1 = q0, q2 = q0, q3 = q0;                                  \
                float f1 = 0.f, f2 = 0.f, f3 = 0.f;                             \
                if (m) { q1 = __builtin_ctzll(m); m &= m - 1; f1 = 1.f; }       \
                if (m) { q2 = __builtin_ctzll(m); m &= m - 1; f2 = 1.f; }       \
                if (m) { q3 = __builtin_ctzll(m); m &= m - 1; f3 = 1.f; }       \
                float w0 = 0.f, w1 = 0.f, w2 = 0.f, w3 = 0.f;                   \
                if (lane < NPN) {                                               \
                    w0 = ln_to_pn[q0 * NPN + lane];                             \
                    w1 = ln_to_pn[q1 * NPN + lane];                             \
                    w2 = ln_to_pn[q2 * NPN + lane];                             \
                    w3 = ln_to_pn[q3 * NPN + lane];                             \
                }                                                               \
                h += w0; h += f1 * w1; h += f2 * w2; h += f3 * w3;              \
            }                                                                   \
        }                                                                       \
        bool sp = false;                                                        \
        if (lane < NPN) {                                                       \
            v_pn = ALPHA * v_pn + apn - h;                                      \
            sp = (v_pn - VTH) > 0.f;                                            \
            if (sp) v_pn = 0.f;                                                 \
        }                                                                       \
        const unsigned long long mPn = __ballot(sp);                            \
        if (lane == 0) sM[slot] = mPn;                                          \
    } while (0)

    if (producer) SMALLNET_STEP(0);
    __syncthreads();   // sM[0] visible

    // ---------------- time loop: 1 barrier per step ----------------
    for (int t = 0; t < NSTEPS; ++t) {
        if (!producer) {
            // APL from previous step's partials (buffer (t+1)&1; zeros at t=0)
            const float* rp = sRed[(t + 1) & 1];
            const float apl = fmaxf(rp[0] + rp[1] + rp[2] + rp[3], 0.f);

#pragma unroll
            for (int j = 0; j < KPER; ++j) vd[j] = ALPHA * vd[j] - apl * wa2k[j];

            // gather over spiking PNs: 2 rows/batch, 4 float4 loads in flight
            unsigned long long m = sM[t & 1];
            while (m) {
                const int p0 = __builtin_ctzll(m); m &= m - 1;
                int p1 = p0; float f1 = 0.f;
                if (m) { p1 = __builtin_ctzll(m); m &= m - 1; f1 = 1.f; }
                if (act) {
                    const float4* w0 = (const float4*)(pn_to_kc + (long)p0 * NKC + kbase);
                    const float4* w1 = (const float4*)(pn_to_kc + (long)p1 * NKC + kbase);
                    float4 a0 = w0[0], a1 = w0[1];
                    float4 b0 = w1[0], b1 = w1[1];
                    vd[0] += a0.x; vd[1] += a0.y; vd[2] += a0.z; vd[3] += a0.w;
                    vd[4] += a1.x; vd[5] += a1.y; vd[6] += a1.z; vd[7] += a1.w;
                    vd[0] += f1 * b0.x; vd[1] += f1 * b0.y; vd[2] += f1 * b0.z; vd[3] += f1 * b0.w;
                    vd[4] += f1 * b1.x; vd[5] += f1 * b1.y; vd[6] += f1 * b1.z; vd[7] += f1 * b1.w;
                }
            }

            float aplp = 0.f;
#pragma unroll
            for (int j = 0; j < KPER; ++j) {
                va[j] = ALPHA * va[j] + GSOMA * (vd[j] - va[j]);
                float s = (va[j] - VTH) > 0.f ? 1.f : 0.f;
                va[j] *= (1.f - s);
                cnt[j] += s;
                aplp += s * wk2a[j];
            }
            for (int off = 32; off > 0; off >>= 1) aplp += __shfl_xor(aplp, off, 64);
            if (lane == 0) sRed[t & 1][wid] = aplp;
        } else if (t < NSTEPS - 1) {
            SMALLNET_STEP((t + 1) & 1);   // one step ahead
        }
        __syncthreads();   // sM[(t+1)&1] + sRed[t&1] visible for step t+1
    }

    // ---------------- epilogue: logits = (cnt/20) @ dec_w + dec_b ----------------
    if (!producer) {
        float acc[NOD];
#pragma unroll
        for (int o = 0; o < NOD; ++o) acc[o] = 0.f;
        if (act) {
#pragma unroll
            for (int j = 0; j < KPER; ++j) {
                float r = cnt[j] / 20.0f;
                if (r != 0.f) {                      // KC sparsity: skip silent KCs
                    const float* wr = dec_w + (long)(kbase + j) * NOD;
#pragma unroll
                    for (int o = 0; o < NOD; ++o) acc[o] += r * wr[o];
                }
            }
        }
#pragma unroll
        for (int o = 0; o < NOD; ++o) {
            float v = acc[o];
            for (int off = 32; off > 0; off >>= 1) v += __shfl_xor(v, off, 64);
            if (lane == 0) sRed2[wid * NOD + o] = v;
        }
    }
    __syncthreads();
    if (tid < NOD) {
        float v = sRed2[tid] + sRed2[NOD + tid] + sRed2[2 * NOD + tid] +
                  sRed2[3 * NOD + tid] + dec_b[tid];
        out[(long)b * NOD + tid] = v;
    }
#undef SMALLNET_STEP
}

extern "C" void kernel_launch(void* const* d_in, const int* in_sizes, int n_in,
                              void* d_out, int out_size, void* d_ws, size_t ws_size,
                              hipStream_t stream) {
    (void)n_in; (void)out_size; (void)d_ws; (void)ws_size;
    const float* or_input  = (const float*)d_in[0];
    const float* or_gains  = (const float*)d_in[1];
    const float* mapping   = (const float*)d_in[2];
    const float* orn_to_pn = (const float*)d_in[3];
    const float* orn_to_ln = (const float*)d_in[4];
    const float* ln_to_pn  = (const float*)d_in[5];
    const float* pn_to_kc  = (const float*)d_in[6];
    const float* kc_to_apl = (const float*)d_in[7];
    const float* apl_to_kc = (const float*)d_in[8];
    const float* dec_w     = (const float*)d_in[9];
    const float* dec_b     = (const float*)d_in[10];
    float* out = (float*)d_out;

    const int batch = in_sizes[0] / NOR;  // 4096
    hipLaunchKernelGGL(snn_fused1, dim3(batch), dim3(TPB), 0, stream,
                       or_input, or_gains, mapping, orn_to_pn, orn_to_ln,
                       ln_to_pn, pn_to_kc, kc_to_apl, apl_to_kc, dec_w, dec_b, out);
}